// Round 8
// baseline (837.968 us; speedup 1.0000x reference)
//
#include <hip/hip_runtime.h>

typedef unsigned short ushort_t;
typedef __attribute__((ext_vector_type(8))) short bf16x8;
typedef __attribute__((ext_vector_type(4))) float f32x4;
typedef __attribute__((ext_vector_type(4))) unsigned int u32x4;

#define ZF 0.9770840884556017f  /* 1/sqrt(2*pi/6) */
#define SQ2 1.4142135623730951f

__device__ __forceinline__ ushort_t f2bf(float f) {
    unsigned u = __float_as_uint(f);
    unsigned r = (u + 0x7fffu + ((u >> 16) & 1u)) >> 16;
    return (ushort_t)r;
}
__device__ __forceinline__ float bf2f(ushort_t h) {
    return __uint_as_float(((unsigned)h) << 16);
}

// ---------------- modulation ----------------
__global__ void kzero(float* ssum) { if (threadIdx.x == 0) ssum[0] = 0.f; }

__global__ __launch_bounds__(128) void ks(const float* __restrict__ w,
                                          const float* __restrict__ aw,
                                          const float* __restrict__ ab,
                                          float* sbuf, float* ssum) {
    int b = blockIdx.x, c = threadIdx.x;
    const float4* wp = (const float4*)(w + b * 512);
    const float4* ap = (const float4*)(aw + c * 512);
    float acc = 0.f;
    for (int k = 0; k < 128; ++k) {
        float4 xv = wp[k], yv = ap[k];
        acc += xv.x * yv.x + xv.y * yv.y + xv.z * yv.z + xv.w * yv.w;
    }
    float s = acc * 0.04419417382415922f + ab[c];  // 1/sqrt(512)
    sbuf[b * 128 + c] = s;
    float sq = s * s;
#pragma unroll
    for (int m = 1; m < 64; m <<= 1) sq += __shfl_xor(sq, m);
    if ((c & 63) == 0) atomicAdd(ssum, sq);
}

__global__ __launch_bounds__(128) void kkn(const float* __restrict__ kw,
                                           const float* __restrict__ ssum,
                                           float* kn, float* srstd) {
    int o = blockIdx.x, t = threadIdx.x;
    float acc = 0.f;
    for (int j = t; j < 1152; j += 128) { float v = kw[o * 1152 + j] * ZF; acc += v * v; }
#pragma unroll
    for (int m = 1; m < 64; m <<= 1) acc += __shfl_xor(acc, m);
    __shared__ float red[2];
    if ((t & 63) == 0) red[t >> 6] = acc;
    __syncthreads();
    if (t == 0) {
        kn[o] = ZF * rsqrtf((red[0] + red[1]) * (1.0f / 1152.0f));
        if (o == 0) srstd[0] = rsqrtf(ssum[0] * (1.0f / 2048.0f));
    }
}

__global__ __launch_bounds__(128) void kww(const float* __restrict__ kw,
                                           const float* __restrict__ sbuf,
                                           const float* __restrict__ kn,
                                           const float* __restrict__ srstd,
                                           const float* __restrict__ ema,
                                           ushort_t* __restrict__ wwbf) {
    int o = blockIdx.x, b = blockIdx.y, i = threadIdx.x;
    float sn = sbuf[b * 128 + i] * srstd[0];
    float knv = kn[o];
    const float* kwp = kw + (o * 128 + i) * 9;
    float wv[9];
    float ssq = 0.f;
#pragma unroll
    for (int t = 0; t < 9; ++t) { float v = kwp[t] * knv * sn; wv[t] = v; ssq += v * v; }
#pragma unroll
    for (int m = 1; m < 64; m <<= 1) ssq += __shfl_xor(ssq, m);
    __shared__ float red[2];
    if ((i & 63) == 0) red[i >> 6] = ssq;
    __syncthreads();
    float tot = red[0] + red[1];
    float g = rsqrtf(tot + 1e-8f) * rsqrtf(ema[0]);
#pragma unroll
    for (int t = 0; t < 9; ++t)
        wwbf[((size_t)(b * 128 + o)) * 1152 + t * 128 + i] = f2bf(wv[t] * g);
}

// ---------------- transpose x -> xT[b][h][w][cin] bf16 ----------------
__global__ __launch_bounds__(256) void kT(const float* __restrict__ x, ushort_t* __restrict__ xT) {
    int h = blockIdx.x, b = blockIdx.y;
    __shared__ ushort_t tile[128 * 132];
    int tid = threadIdx.x;
    const float* xb = x + (size_t)b * 2097152 + (size_t)h * 128;
#pragma unroll 4
    for (int it = 0; it < 16; ++it) {
        int idx = it * 256 + tid;
        int cin = idx >> 5, c4 = idx & 31;
        float4 v = *(const float4*)(xb + (size_t)cin * 16384 + c4 * 4);
        union { ushort_t us[4]; unsigned long long u; } p;
        p.us[0] = f2bf(v.x); p.us[1] = f2bf(v.y); p.us[2] = f2bf(v.z); p.us[3] = f2bf(v.w);
        *(unsigned long long*)(tile + cin * 132 + c4 * 4) = p.u;
    }
    __syncthreads();
    ushort_t* ob = xT + ((size_t)(b * 128 + h)) * 16384;
#pragma unroll 2
    for (int it = 0; it < 8; ++it) {
        int idx = it * 256 + tid;
        int wcol = idx >> 4;
        int cinb = (idx & 15) << 3;
        union { ushort_t us[8]; u32x4 v; } p;
#pragma unroll
        for (int j = 0; j < 8; ++j) p.us[j] = tile[(cinb + j) * 132 + wcol];
        *(u32x4*)(ob + (size_t)wcol * 128 + cinb) = p.v;
    }
}

// ---------------- conv: implicit GEMM, MFMA bf16 (v2: 8x16 pixel tile) ----------------
__global__ __launch_bounds__(256) void kC(const ushort_t* __restrict__ xT,
                                          const ushort_t* __restrict__ wwbf,
                                          ushort_t* __restrict__ ybf) {
    const int b = blockIdx.y;
    const int tile = blockIdx.x;          // 0..127
    const int R0 = (tile >> 3) * 8;       // 16 row-tiles
    const int C0 = (tile & 7) * 16;       // 8 col-tiles
    const int tid = threadIdx.x;
    const int wid = tid >> 6;
    const int lane = tid & 63;
    const int lr = lane & 15;
    const int lg = lane >> 4;

    __shared__ __align__(16) unsigned char xs[10 * 18 * 128 * 2];  // 46080 B

    const ushort_t* xTb = xT + (size_t)b * 2097152;
    for (int q = tid; q < 2880; q += 256) {
        int cinb = (q & 15) << 3;
        int rc = q >> 4;                  // 0..179
        int row = rc / 18;
        int col = rc - row * 18;
        int gr = R0 - 1 + row, gc = C0 - 1 + col;
        u32x4 v = {0u, 0u, 0u, 0u};
        if ((unsigned)gr < 128u && (unsigned)gc < 128u)
            v = *(const u32x4*)(xTb + (((size_t)(gr << 7) + gc) << 7) + cinb);
        int byte = (rc << 8) + (cinb << 1);
        byte ^= (col & 7) << 4;
        *(u32x4*)(xs + byte) = v;
    }
    __syncthreads();

    const ushort_t* wwp = wwbf + ((size_t)(b * 128 + wid * 32)) * 1152;
    f32x4 acc[2][8] = {};
#pragma unroll 1
    for (int tap = 0; tap < 9; ++tap) {
        const int dr = tap / 3, dc = tap - dr * 3;
#pragma unroll
        for (int kq = 0; kq < 4; ++kq) {
            const int kloc = kq * 32 + lg * 8;
            const int kglob = tap * 128 + kloc;
            bf16x8 a0 = *(const bf16x8*)(wwp + lr * 1152 + kglob);
            bf16x8 a1 = *(const bf16x8*)(wwp + (lr + 16) * 1152 + kglob);
#pragma unroll
            for (int nf = 0; nf < 8; ++nf) {
                int col = lr + dc;
                int byte = (((nf + dr) * 18 + col) << 8) + (kloc << 1);
                byte ^= (col & 7) << 4;
                bf16x8 bfr = *(const bf16x8*)(xs + byte);
                acc[0][nf] = __builtin_amdgcn_mfma_f32_16x16x32_bf16(a0, bfr, acc[0][nf], 0, 0, 0);
                acc[1][nf] = __builtin_amdgcn_mfma_f32_16x16x32_bf16(a1, bfr, acc[1][nf], 0, 0, 0);
            }
        }
    }

    ushort_t* yb = ybf + (size_t)b * 2097152;
#pragma unroll
    for (int mf = 0; mf < 2; ++mf)
#pragma unroll
        for (int nf = 0; nf < 8; ++nf)
#pragma unroll
            for (int r = 0; r < 4; ++r) {
                int cout = wid * 32 + mf * 16 + lg * 4 + r;
                int row = R0 + nf, colp = C0 + lr;
                yb[(((size_t)cout << 7) + row) * 128 + colp] = f2bf(acc[mf][nf][r]);
            }
}

// ---------------- fused filtered_lrelu (v3: stride-77 z, quad pass3, border strips) ----------------
__global__ __launch_bounds__(256) void kF(const ushort_t* __restrict__ ybf,
                                          const float* __restrict__ bias,
                                          const float* __restrict__ upf,
                                          const float* __restrict__ dnf,
                                          float* __restrict__ out) {
    int tileid = blockIdx.x, co = blockIdx.y, b = blockIdx.z;
    int R0 = (tileid >> 2) * 32, C0 = (tileid & 3) * 32;
    int tid = threadIdx.x;
    __shared__ float A[74 * 77];   // y patch (42x44) -> z (74 rows, stride 77)
    __shared__ float Bm[42 * 76];  // col-up (42x74 @76) -> d1 (74x33)

    // uniform filter loads -> scalar registers
    float fue[6], fuo[6], fre[6], fro[6], fd[12];
#pragma unroll
    for (int m = 0; m < 6; ++m) {
        float e = 2.0f * upf[2 * m], o = 2.0f * upf[2 * m + 1];
        fue[m] = e; fuo[m] = o;
        fre[m] = SQ2 * e; fro[m] = SQ2 * o;
    }
#pragma unroll
    for (int j = 0; j < 12; ++j) fd[j] = dnf[j];
    float bv = SQ2 * bias[co];

    const ushort_t* ych = ybf + ((size_t)(b * 128 + co) << 14);
    int yr0 = R0 - 5, yc0 = C0 - 5;
    // pass 1: load 42x42 y patch (stride 44)
    for (int idx = tid; idx < 1764; idx += 256) {
        int r = idx / 42, c = idx - r * 42;
        int gr = yr0 + r, gc = yc0 + c;
        float v = 0.f;
        if ((unsigned)gr < 128u && (unsigned)gc < 128u) v = bf2f(ych[(gr << 7) + gc]);
        A[r * 44 + c] = v;
    }
    __syncthreads();
    // pass 2: col-upsample, polyphase pair (uc=2k: odd taps, uc=2k+1: even taps)
    for (int it = tid; it < 42 * 37; it += 256) {
        int r = it / 37, k = it - r * 37;
        const float* yr = A + r * 44 + k;
        float y0 = yr[0], y1 = yr[1], y2 = yr[2], y3 = yr[3], y4 = yr[4], y5 = yr[5];
        float s0 = fuo[0] * y0 + fuo[1] * y1 + fuo[2] * y2 + fuo[3] * y3 + fuo[4] * y4 + fuo[5] * y5;
        float s1 = fue[0] * y0 + fue[1] * y1 + fue[2] * y2 + fue[3] * y3 + fue[4] * y4 + fue[5] * y5;
        float2 sv; sv.x = s0; sv.y = s1;
        *(float2*)(Bm + r * 76 + 2 * k) = sv;
    }
    __syncthreads();
    // pass 3: row-upsample (sqrt2+bias folded) + lrelu + clamp, 2x2 quad per item -> z in A (stride 77)
    for (int it = tid; it < 37 * 37; it += 256) {
        int kr = it / 37, jc = it - kr * 37;
        const float* bc = Bm + kr * 76 + 2 * jc;
        float2 c0 = *(const float2*)(bc);
        float2 c1 = *(const float2*)(bc + 76);
        float2 c2 = *(const float2*)(bc + 152);
        float2 c3 = *(const float2*)(bc + 228);
        float2 c4 = *(const float2*)(bc + 304);
        float2 c5 = *(const float2*)(bc + 380);
        float t00 = bv + fro[0] * c0.x + fro[1] * c1.x + fro[2] * c2.x + fro[3] * c3.x + fro[4] * c4.x + fro[5] * c5.x;
        float t01 = bv + fro[0] * c0.y + fro[1] * c1.y + fro[2] * c2.y + fro[3] * c3.y + fro[4] * c4.y + fro[5] * c5.y;
        float t10 = bv + fre[0] * c0.x + fre[1] * c1.x + fre[2] * c2.x + fre[3] * c3.x + fre[4] * c4.x + fre[5] * c5.x;
        float t11 = bv + fre[0] * c0.y + fre[1] * c1.y + fre[2] * c2.y + fre[3] * c3.y + fre[4] * c4.y + fre[5] * c5.y;
        t00 = fmaxf(t00, 0.f) + 0.2f * fminf(t00, 0.f);
        t01 = fmaxf(t01, 0.f) + 0.2f * fminf(t01, 0.f);
        t10 = fmaxf(t10, 0.f) + 0.2f * fminf(t10, 0.f);
        t11 = fmaxf(t11, 0.f) + 0.2f * fminf(t11, 0.f);
        t00 = fminf(fmaxf(t00, -256.f), 256.f);
        t01 = fminf(fmaxf(t01, -256.f), 256.f);
        t10 = fminf(fmaxf(t10, -256.f), 256.f);
        t11 = fminf(fmaxf(t11, -256.f), 256.f);
        float* zp = A + (2 * kr) * 77 + 2 * jc;
        zp[0] = t00; zp[1] = t01;
        zp[77] = t10; zp[78] = t11;
    }
    __syncthreads();
    // border-strip zeroing (invalid up-pixels must be 0); uniform branches, 5-wide strips
    {
        bool tz = (R0 == 0), bz = (R0 == 96), lz = (C0 == 0), rz = (C0 == 96);
        if (tz || bz) {
            for (int idx = tid; idx < 370; idx += 256) {
                int s = idx / 74, c = idx - s * 74;
                if (tz) A[s * 77 + c] = 0.f;
                if (bz) A[(69 + s) * 77 + c] = 0.f;
            }
        }
        if (lz || rz) {
            for (int idx = tid; idx < 370; idx += 256) {
                int r = idx / 5, s = idx - r * 5;
                if (lz) A[r * 77 + s] = 0.f;
                if (rz) A[r * 77 + 69 + s] = 0.f;
            }
        }
        if (tz || bz || lz || rz) __syncthreads();
    }
    // pass 4: col-downsample, 4 outputs/thread from 18-float window -> d1 (stride 33)
    for (int it = tid; it < 74 * 8; it += 256) {
        int ur = it >> 3, q = it & 7;
        const float* z = A + ur * 77 + 8 * q;
        float4 w0 = *(const float4*)(z);
        float4 w1 = *(const float4*)(z + 4);
        float4 w2 = *(const float4*)(z + 8);
        float4 w3 = *(const float4*)(z + 12);
        float2 w4 = *(const float2*)(z + 16);
        float win[18] = {w0.x, w0.y, w0.z, w0.w, w1.x, w1.y, w1.z, w1.w,
                         w2.x, w2.y, w2.z, w2.w, w3.x, w3.y, w3.z, w3.w, w4.x, w4.y};
        float* dp = Bm + ur * 33 + 4 * q;
#pragma unroll
        for (int i = 0; i < 4; ++i) {
            float s = 0.f;
#pragma unroll
            for (int j = 0; j < 12; ++j) s += fd[j] * win[2 * i + j];
            dp[i] = s;
        }
    }
    __syncthreads();
    // pass 5: row-downsample, 4 outputs/thread, write global
    {
        int qr = tid >> 5, oc = tid & 31;
        const float* d = Bm + (8 * qr) * 33 + oc;
        float win[18];
#pragma unroll
        for (int j = 0; j < 18; ++j) win[j] = d[j * 33];
        float* ob = out + (((size_t)(b * 128 + co) << 7) + R0) * 128 + C0 + oc;
#pragma unroll
        for (int i = 0; i < 4; ++i) {
            float s = 0.f;
#pragma unroll
            for (int j = 0; j < 12; ++j) s += fd[j] * win[2 * i + j];
            ob[(4 * qr + i) * 128] = s;
        }
    }
}

extern "C" void kernel_launch(void* const* d_in, const int* in_sizes, int n_in,
                              void* d_out, int out_size, void* d_ws, size_t ws_size,
                              hipStream_t stream) {
    const float* x    = (const float*)d_in[0];
    const float* w    = (const float*)d_in[1];
    const float* aw   = (const float*)d_in[2];
    const float* ab   = (const float*)d_in[3];
    const float* kw   = (const float*)d_in[4];
    const float* bias = (const float*)d_in[5];
    const float* upf  = (const float*)d_in[6];
    const float* dnf  = (const float*)d_in[7];
    const float* ema  = (const float*)d_in[8];
    float* out = (float*)d_out;
    char* ws = (char*)d_ws;

    float* sbuf  = (float*)ws;
    float* ssum  = (float*)(ws + 8192);
    float* srstd = (float*)(ws + 8196);
    float* kn    = (float*)(ws + 8448);
    ushort_t* wwbf = (ushort_t*)(ws + 16384);
    ushort_t* xT   = (ushort_t*)(ws + ((size_t)5 << 20));
    ushort_t* ybf  = (ushort_t*)(ws + ((size_t)5 << 20) + ((size_t)64 << 20));

    kzero<<<1, 64, 0, stream>>>(ssum);
    ks<<<16, 128, 0, stream>>>(w, aw, ab, sbuf, ssum);
    kkn<<<128, 128, 0, stream>>>(kw, ssum, kn, srstd);
    kww<<<dim3(128, 16), 128, 0, stream>>>(kw, sbuf, kn, srstd, ema, wwbf);
    kT<<<dim3(128, 16), 256, 0, stream>>>(x, xT);
    kC<<<dim3(128, 16), 256, 0, stream>>>(xT, wwbf, ybf);
    kF<<<dim3(16, 128, 16), 256, 0, stream>>>(ybf, bias, upf, dnf, out);
}

// Round 9
// 597.889 us; speedup vs baseline: 1.4015x; 1.4015x over previous
//
#include <hip/hip_runtime.h>

typedef unsigned short ushort_t;
typedef __attribute__((ext_vector_type(8))) short bf16x8;
typedef __attribute__((ext_vector_type(4))) float f32x4;
typedef __attribute__((ext_vector_type(4))) unsigned int u32x4;

#define ZF 0.9770840884556017f  /* 1/sqrt(2*pi/6) */
#define SQ2 1.4142135623730951f

__device__ __forceinline__ ushort_t f2bf(float f) {
    unsigned u = __float_as_uint(f);
    unsigned r = (u + 0x7fffu + ((u >> 16) & 1u)) >> 16;
    return (ushort_t)r;
}
__device__ __forceinline__ float bf2f(ushort_t h) {
    return __uint_as_float(((unsigned)h) << 16);
}

// ---------------- modulation ----------------
__global__ void kzero(float* ssum) { if (threadIdx.x == 0) ssum[0] = 0.f; }

__global__ __launch_bounds__(128) void ks(const float* __restrict__ w,
                                          const float* __restrict__ aw,
                                          const float* __restrict__ ab,
                                          float* sbuf, float* ssum) {
    int b = blockIdx.x, c = threadIdx.x;
    const float4* wp = (const float4*)(w + b * 512);
    const float4* ap = (const float4*)(aw + c * 512);
    float acc = 0.f;
    for (int k = 0; k < 128; ++k) {
        float4 xv = wp[k], yv = ap[k];
        acc += xv.x * yv.x + xv.y * yv.y + xv.z * yv.z + xv.w * yv.w;
    }
    float s = acc * 0.04419417382415922f + ab[c];  // 1/sqrt(512)
    sbuf[b * 128 + c] = s;
    float sq = s * s;
#pragma unroll
    for (int m = 1; m < 64; m <<= 1) sq += __shfl_xor(sq, m);
    if ((c & 63) == 0) atomicAdd(ssum, sq);
}

__global__ __launch_bounds__(128) void kkn(const float* __restrict__ kw,
                                           const float* __restrict__ ssum,
                                           float* kn, float* srstd) {
    int o = blockIdx.x, t = threadIdx.x;
    float acc = 0.f;
    for (int j = t; j < 1152; j += 128) { float v = kw[o * 1152 + j] * ZF; acc += v * v; }
#pragma unroll
    for (int m = 1; m < 64; m <<= 1) acc += __shfl_xor(acc, m);
    __shared__ float red[2];
    if ((t & 63) == 0) red[t >> 6] = acc;
    __syncthreads();
    if (t == 0) {
        kn[o] = ZF * rsqrtf((red[0] + red[1]) * (1.0f / 1152.0f));
        if (o == 0) srstd[0] = rsqrtf(ssum[0] * (1.0f / 2048.0f));
    }
}

__global__ __launch_bounds__(128) void kww(const float* __restrict__ kw,
                                           const float* __restrict__ sbuf,
                                           const float* __restrict__ kn,
                                           const float* __restrict__ srstd,
                                           const float* __restrict__ ema,
                                           ushort_t* __restrict__ wwbf) {
    int o = blockIdx.x, b = blockIdx.y, i = threadIdx.x;
    float sn = sbuf[b * 128 + i] * srstd[0];
    float knv = kn[o];
    const float* kwp = kw + (o * 128 + i) * 9;
    float wv[9];
    float ssq = 0.f;
#pragma unroll
    for (int t = 0; t < 9; ++t) { float v = kwp[t] * knv * sn; wv[t] = v; ssq += v * v; }
#pragma unroll
    for (int m = 1; m < 64; m <<= 1) ssq += __shfl_xor(ssq, m);
    __shared__ float red[2];
    if ((i & 63) == 0) red[i >> 6] = ssq;
    __syncthreads();
    float tot = red[0] + red[1];
    float g = rsqrtf(tot + 1e-8f) * rsqrtf(ema[0]);
#pragma unroll
    for (int t = 0; t < 9; ++t)
        wwbf[((size_t)(b * 128 + o)) * 1152 + t * 128 + i] = f2bf(wv[t] * g);
}

// ---------------- transpose x -> xT[b][h][w][cin] bf16 ----------------
__global__ __launch_bounds__(256) void kT(const float* __restrict__ x, ushort_t* __restrict__ xT) {
    int h = blockIdx.x, b = blockIdx.y;
    __shared__ ushort_t tile[128 * 132];
    int tid = threadIdx.x;
    const float* xb = x + (size_t)b * 2097152 + (size_t)h * 128;
#pragma unroll 4
    for (int it = 0; it < 16; ++it) {
        int idx = it * 256 + tid;
        int cin = idx >> 5, c4 = idx & 31;
        float4 v = *(const float4*)(xb + (size_t)cin * 16384 + c4 * 4);
        union { ushort_t us[4]; unsigned long long u; } p;
        p.us[0] = f2bf(v.x); p.us[1] = f2bf(v.y); p.us[2] = f2bf(v.z); p.us[3] = f2bf(v.w);
        *(unsigned long long*)(tile + cin * 132 + c4 * 4) = p.u;
    }
    __syncthreads();
    ushort_t* ob = xT + ((size_t)(b * 128 + h)) * 16384;
#pragma unroll 2
    for (int it = 0; it < 8; ++it) {
        int idx = it * 256 + tid;
        int wcol = idx >> 4;
        int cinb = (idx & 15) << 3;
        union { ushort_t us[8]; u32x4 v; } p;
#pragma unroll
        for (int j = 0; j < 8; ++j) p.us[j] = tile[(cinb + j) * 132 + wcol];
        *(u32x4*)(ob + (size_t)wcol * 128 + cinb) = p.v;
    }
}

// ---------------- conv: implicit GEMM, MFMA bf16 (v2: 8x16 pixel tile) ----------------
__global__ __launch_bounds__(256) void kC(const ushort_t* __restrict__ xT,
                                          const ushort_t* __restrict__ wwbf,
                                          ushort_t* __restrict__ ybf) {
    const int b = blockIdx.y;
    const int tile = blockIdx.x;          // 0..127
    const int R0 = (tile >> 3) * 8;       // 16 row-tiles
    const int C0 = (tile & 7) * 16;       // 8 col-tiles
    const int tid = threadIdx.x;
    const int wid = tid >> 6;
    const int lane = tid & 63;
    const int lr = lane & 15;
    const int lg = lane >> 4;

    __shared__ __align__(16) unsigned char xs[10 * 18 * 128 * 2];  // 46080 B

    const ushort_t* xTb = xT + (size_t)b * 2097152;
    for (int q = tid; q < 2880; q += 256) {
        int cinb = (q & 15) << 3;
        int rc = q >> 4;                  // 0..179
        int row = rc / 18;
        int col = rc - row * 18;
        int gr = R0 - 1 + row, gc = C0 - 1 + col;
        u32x4 v = {0u, 0u, 0u, 0u};
        if ((unsigned)gr < 128u && (unsigned)gc < 128u)
            v = *(const u32x4*)(xTb + (((size_t)(gr << 7) + gc) << 7) + cinb);
        int byte = (rc << 8) + (cinb << 1);
        byte ^= (col & 7) << 4;
        *(u32x4*)(xs + byte) = v;
    }
    __syncthreads();

    const ushort_t* wwp = wwbf + ((size_t)(b * 128 + wid * 32)) * 1152;
    f32x4 acc[2][8] = {};
#pragma unroll 1
    for (int tap = 0; tap < 9; ++tap) {
        const int dr = tap / 3, dc = tap - dr * 3;
#pragma unroll
        for (int kq = 0; kq < 4; ++kq) {
            const int kloc = kq * 32 + lg * 8;
            const int kglob = tap * 128 + kloc;
            bf16x8 a0 = *(const bf16x8*)(wwp + lr * 1152 + kglob);
            bf16x8 a1 = *(const bf16x8*)(wwp + (lr + 16) * 1152 + kglob);
#pragma unroll
            for (int nf = 0; nf < 8; ++nf) {
                int col = lr + dc;
                int byte = (((nf + dr) * 18 + col) << 8) + (kloc << 1);
                byte ^= (col & 7) << 4;
                bf16x8 bfr = *(const bf16x8*)(xs + byte);
                acc[0][nf] = __builtin_amdgcn_mfma_f32_16x16x32_bf16(a0, bfr, acc[0][nf], 0, 0, 0);
                acc[1][nf] = __builtin_amdgcn_mfma_f32_16x16x32_bf16(a1, bfr, acc[1][nf], 0, 0, 0);
            }
        }
    }

    ushort_t* yb = ybf + (size_t)b * 2097152;
#pragma unroll
    for (int mf = 0; mf < 2; ++mf)
#pragma unroll
        for (int nf = 0; nf < 8; ++nf)
#pragma unroll
            for (int r = 0; r < 4; ++r) {
                int cout = wid * 32 + mf * 16 + lg * 4 + r;
                int row = R0 + nf, colp = C0 + lr;
                yb[(((size_t)cout << 7) + row) * 128 + colp] = f2bf(acc[mf][nf][r]);
            }
}

// ---------------- fused filtered_lrelu (v4: stride-77 z + SCALAR pass-4 reads) ----------------
__global__ __launch_bounds__(256) void kF(const ushort_t* __restrict__ ybf,
                                          const float* __restrict__ bias,
                                          const float* __restrict__ upf,
                                          const float* __restrict__ dnf,
                                          float* __restrict__ out) {
    int tileid = blockIdx.x, co = blockIdx.y, b = blockIdx.z;
    int R0 = (tileid >> 2) * 32, C0 = (tileid & 3) * 32;
    int tid = threadIdx.x;
    __shared__ float A[74 * 77];   // y patch (42x44) -> z (74 rows, stride 77)
    __shared__ float Bm[42 * 76];  // col-up (42x74 @76) -> d1 (74x33)

    // uniform filter loads -> scalar registers
    float fue[6], fuo[6], fre[6], fro[6], fd[12];
#pragma unroll
    for (int m = 0; m < 6; ++m) {
        float e = 2.0f * upf[2 * m], o = 2.0f * upf[2 * m + 1];
        fue[m] = e; fuo[m] = o;
        fre[m] = SQ2 * e; fro[m] = SQ2 * o;
    }
#pragma unroll
    for (int j = 0; j < 12; ++j) fd[j] = dnf[j];
    float bv = SQ2 * bias[co];

    const ushort_t* ych = ybf + ((size_t)(b * 128 + co) << 14);
    int yr0 = R0 - 5, yc0 = C0 - 5;
    // pass 1: load 42x42 y patch (stride 44)
    for (int idx = tid; idx < 1764; idx += 256) {
        int r = idx / 42, c = idx - r * 42;
        int gr = yr0 + r, gc = yc0 + c;
        float v = 0.f;
        if ((unsigned)gr < 128u && (unsigned)gc < 128u) v = bf2f(ych[(gr << 7) + gc]);
        A[r * 44 + c] = v;
    }
    __syncthreads();
    // pass 2: col-upsample, polyphase pair (uc=2k: odd taps, uc=2k+1: even taps)
    for (int it = tid; it < 42 * 37; it += 256) {
        int r = it / 37, k = it - r * 37;
        const float* yr = A + r * 44 + k;
        float y0 = yr[0], y1 = yr[1], y2 = yr[2], y3 = yr[3], y4 = yr[4], y5 = yr[5];
        float s0 = fuo[0] * y0 + fuo[1] * y1 + fuo[2] * y2 + fuo[3] * y3 + fuo[4] * y4 + fuo[5] * y5;
        float s1 = fue[0] * y0 + fue[1] * y1 + fue[2] * y2 + fue[3] * y3 + fue[4] * y4 + fue[5] * y5;
        float2 sv; sv.x = s0; sv.y = s1;
        *(float2*)(Bm + r * 76 + 2 * k) = sv;
    }
    __syncthreads();
    // pass 3: row-upsample (sqrt2+bias folded) + lrelu + clamp, 2x2 quad per item -> z in A (stride 77)
    for (int it = tid; it < 37 * 37; it += 256) {
        int kr = it / 37, jc = it - kr * 37;
        const float* bc = Bm + kr * 76 + 2 * jc;
        float2 c0 = *(const float2*)(bc);
        float2 c1 = *(const float2*)(bc + 76);
        float2 c2 = *(const float2*)(bc + 152);
        float2 c3 = *(const float2*)(bc + 228);
        float2 c4 = *(const float2*)(bc + 304);
        float2 c5 = *(const float2*)(bc + 380);
        float t00 = bv + fro[0] * c0.x + fro[1] * c1.x + fro[2] * c2.x + fro[3] * c3.x + fro[4] * c4.x + fro[5] * c5.x;
        float t01 = bv + fro[0] * c0.y + fro[1] * c1.y + fro[2] * c2.y + fro[3] * c3.y + fro[4] * c4.y + fro[5] * c5.y;
        float t10 = bv + fre[0] * c0.x + fre[1] * c1.x + fre[2] * c2.x + fre[3] * c3.x + fre[4] * c4.x + fre[5] * c5.x;
        float t11 = bv + fre[0] * c0.y + fre[1] * c1.y + fre[2] * c2.y + fre[3] * c3.y + fre[4] * c4.y + fre[5] * c5.y;
        t00 = fmaxf(t00, 0.f) + 0.2f * fminf(t00, 0.f);
        t01 = fmaxf(t01, 0.f) + 0.2f * fminf(t01, 0.f);
        t10 = fmaxf(t10, 0.f) + 0.2f * fminf(t10, 0.f);
        t11 = fmaxf(t11, 0.f) + 0.2f * fminf(t11, 0.f);
        t00 = fminf(fmaxf(t00, -256.f), 256.f);
        t01 = fminf(fmaxf(t01, -256.f), 256.f);
        t10 = fminf(fmaxf(t10, -256.f), 256.f);
        t11 = fminf(fmaxf(t11, -256.f), 256.f);
        float* zp = A + (2 * kr) * 77 + 2 * jc;
        zp[0] = t00; zp[1] = t01;
        zp[77] = t10; zp[78] = t11;
    }
    __syncthreads();
    // border-strip zeroing (invalid up-pixels must be 0); uniform branches, 5-wide strips
    {
        bool tz = (R0 == 0), bz = (R0 == 96), lz = (C0 == 0), rz = (C0 == 96);
        if (tz || bz) {
            for (int idx = tid; idx < 370; idx += 256) {
                int s = idx / 74, c = idx - s * 74;
                if (tz) A[s * 77 + c] = 0.f;
                if (bz) A[(69 + s) * 77 + c] = 0.f;
            }
        }
        if (lz || rz) {
            for (int idx = tid; idx < 370; idx += 256) {
                int r = idx / 5, s = idx - r * 5;
                if (lz) A[r * 77 + s] = 0.f;
                if (rz) A[r * 77 + 69 + s] = 0.f;
            }
        }
        if (tz || bz || lz || rz) __syncthreads();
    }
    // pass 4: col-downsample, 4 outputs/thread, SCALAR reads (stride 77 -> 2-way banks = free)
    for (int it = tid; it < 74 * 8; it += 256) {
        int ur = it >> 3, q = it & 7;
        const float* z = A + ur * 77 + 8 * q;
        float win[18];
#pragma unroll
        for (int j = 0; j < 18; ++j) win[j] = z[j];
        float* dp = Bm + ur * 33 + 4 * q;
#pragma unroll
        for (int i = 0; i < 4; ++i) {
            float s = 0.f;
#pragma unroll
            for (int j = 0; j < 12; ++j) s += fd[j] * win[2 * i + j];
            dp[i] = s;
        }
    }
    __syncthreads();
    // pass 5: row-downsample, 4 outputs/thread, write global
    {
        int qr = tid >> 5, oc = tid & 31;
        const float* d = Bm + (8 * qr) * 33 + oc;
        float win[18];
#pragma unroll
        for (int j = 0; j < 18; ++j) win[j] = d[j * 33];
        float* ob = out + (((size_t)(b * 128 + co) << 7) + R0) * 128 + C0 + oc;
#pragma unroll
        for (int i = 0; i < 4; ++i) {
            float s = 0.f;
#pragma unroll
            for (int j = 0; j < 12; ++j) s += fd[j] * win[2 * i + j];
            ob[(4 * qr + i) * 128] = s;
        }
    }
}

extern "C" void kernel_launch(void* const* d_in, const int* in_sizes, int n_in,
                              void* d_out, int out_size, void* d_ws, size_t ws_size,
                              hipStream_t stream) {
    const float* x    = (const float*)d_in[0];
    const float* w    = (const float*)d_in[1];
    const float* aw   = (const float*)d_in[2];
    const float* ab   = (const float*)d_in[3];
    const float* kw   = (const float*)d_in[4];
    const float* bias = (const float*)d_in[5];
    const float* upf  = (const float*)d_in[6];
    const float* dnf  = (const float*)d_in[7];
    const float* ema  = (const float*)d_in[8];
    float* out = (float*)d_out;
    char* ws = (char*)d_ws;

    float* sbuf  = (float*)ws;
    float* ssum  = (float*)(ws + 8192);
    float* srstd = (float*)(ws + 8196);
    float* kn    = (float*)(ws + 8448);
    ushort_t* wwbf = (ushort_t*)(ws + 16384);
    ushort_t* xT   = (ushort_t*)(ws + ((size_t)5 << 20));
    ushort_t* ybf  = (ushort_t*)(ws + ((size_t)5 << 20) + ((size_t)64 << 20));

    kzero<<<1, 64, 0, stream>>>(ssum);
    ks<<<16, 128, 0, stream>>>(w, aw, ab, sbuf, ssum);
    kkn<<<128, 128, 0, stream>>>(kw, ssum, kn, srstd);
    kww<<<dim3(128, 16), 128, 0, stream>>>(kw, sbuf, kn, srstd, ema, wwbf);
    kT<<<dim3(128, 16), 256, 0, stream>>>(x, xT);
    kC<<<dim3(128, 16), 256, 0, stream>>>(xT, wwbf, ybf);
    kF<<<dim3(16, 128, 16), 256, 0, stream>>>(ybf, bias, upf, dnf, out);
}